// Round 10
// baseline (78.653 us; speedup 1.0000x reference)
//
#include <hip/hip_runtime.h>

// ROI head matcher. R9: tournament-tree argmax (same theory as R8, which hit
// two infra failures — this is a restructured, functionally equivalent build:
// block 256, 2-way GT split, flattened tree, partial outer unroll).
//
// Per group of 8 GTs: 8 independent IoUs, Dekker tree-reduce 8->1 (depth 3),
// one carried merge per group -> loop-carried chain is ~8 merges per wave
// instead of 128 serial compares (~10x less serial latency, equal issue
// count). Every pairing/merge is ascending-index with strict '>' (upper
// replaces only if strictly greater) -> jnp.argmax first-index tie
// semantics exact.
//
// Block = 256 threads = 4 waves; wave w: proposal-half h=w&1, GT-half
// q=w>>1 (64 GTs). Each lane carries 2 proposals (one ds_read_b128 + area
// recompute serves 2 chains). Grid 782 blocks -> ~12 waves/CU; ILP (8
// independent IoUs in flight) covers latency instead of TLP.
//
// Pair compare (exact, absmax 0 across R2-R7):
//   i1/u1 > i2/u2  <=>  (p1+e1) > (p2+e2),  e = fmaf(a,b,-p)
// One IEEE divide in the epilogue reproduces best_match_iou bit-exactly.

#define IOU_THRESHOLD 0.5f
#define LOW_BG_IOU 0.1f
#define BLOCK 256
#define PROPS 256   // proposals per block

struct Cand { float i, u; int g; };

__device__ __forceinline__ Cand merge_up(Cand a, Cand b) {
    // b has strictly higher indices; replaces a only if strictly greater.
    float p1 = b.i * a.u;
    float e1 = fmaf(b.i, a.u, -p1);
    float p2 = a.i * b.u;
    float e2 = fmaf(a.i, b.u, -p2);
    bool gt = (p1 - p2) > (e2 - e1);
    Cand r;
    r.i = gt ? b.i : a.i;
    r.u = gt ? b.u : a.u;
    r.g = gt ? b.g : a.g;
    return r;
}

__global__ __launch_bounds__(BLOCK) void roi_match_kernel(
    const float* __restrict__ proposals,   // [N,4]
    const float* __restrict__ gt_boxes,    // [128,4]
    const int*   __restrict__ gt_labels,   // [128]
    float* __restrict__ out,               // [N] labels then [N,4] boxes
    int N)
{
#pragma clang fp contract(off)
    __shared__ float4 s_gt[128];
    __shared__ float  s_lab[128];
    __shared__ float4 s_part[2][PROPS];    // [gt-half][proposal slot]

    const int tid  = threadIdx.x;
    const int wave = tid >> 6;
    const int lane = tid & 63;
    const int h    = wave & 1;             // proposal half
    const int qt   = wave >> 1;            // GT half
    const int base = blockIdx.x * PROPS;

    if (tid < 128) {
        s_gt[tid]  = ((const float4*)gt_boxes)[tid];
        s_lab[tid] = (float)gt_labels[tid];
    }
    __syncthreads();

    const int slot0 = h * 128 + lane;      // proposal slots within block
    const int slot1 = slot0 + 64;
    const int n0 = base + slot0;
    const int n1 = base + slot1;
    const int c0 = n0 < N ? n0 : N - 1;    // clamp loads; writes guarded
    const int c1 = n1 < N ? n1 : N - 1;
    const float4 P0 = ((const float4*)proposals)[c0];
    const float4 P1 = ((const float4*)proposals)[c1];
    const float a0 = (P0.z - P0.x) * (P0.w - P0.y);
    const float a1 = (P1.z - P1.x) * (P1.w - P1.y);

    const int gbase = qt * 64;
    Cand best0 = {0.0f, 1.0f, gbase};      // iou-0 sentinel at first index
    Cand best1 = {0.0f, 1.0f, gbase};

#pragma unroll 2
    for (int grp = 0; grp < 8; ++grp) {    // 8 groups of 8 GTs
        const int g0 = gbase + grp * 8;
        float4 gb[8];
        float  ga[8];
#pragma unroll
        for (int k = 0; k < 8; ++k) gb[k] = s_gt[g0 + k];
#pragma unroll
        for (int k = 0; k < 8; ++k)
            ga[k] = (gb[k].z - gb[k].x) * (gb[k].w - gb[k].y);  // ref rounding

        // ---- proposal 0: 8 independent IoUs, then depth-3 tree ----
        {
            float iv[8], uv[8];
#pragma unroll
            for (int k = 0; k < 8; ++k) {
                float x1 = fmaxf(gb[k].x, P0.x);
                float y1 = fmaxf(gb[k].y, P0.y);
                float x2 = fminf(gb[k].z, P0.z);
                float y2 = fminf(gb[k].w, P0.w);
                float iw = fmaxf(x2 - x1, 0.0f);
                float ih = fmaxf(y2 - y1, 0.0f);
                iv[k] = iw * ih;
                uv[k] = (ga[k] + a0) - iv[k];
            }
            Cand c01 = merge_up(Cand{iv[0], uv[0], g0 + 0}, Cand{iv[1], uv[1], g0 + 1});
            Cand c23 = merge_up(Cand{iv[2], uv[2], g0 + 2}, Cand{iv[3], uv[3], g0 + 3});
            Cand c45 = merge_up(Cand{iv[4], uv[4], g0 + 4}, Cand{iv[5], uv[5], g0 + 5});
            Cand c67 = merge_up(Cand{iv[6], uv[6], g0 + 6}, Cand{iv[7], uv[7], g0 + 7});
            Cand c03 = merge_up(c01, c23);
            Cand c47 = merge_up(c45, c67);
            best0 = merge_up(best0, merge_up(c03, c47));
        }
        // ---- proposal 1 (independent chain) ----
        {
            float iv[8], uv[8];
#pragma unroll
            for (int k = 0; k < 8; ++k) {
                float x1 = fmaxf(gb[k].x, P1.x);
                float y1 = fmaxf(gb[k].y, P1.y);
                float x2 = fminf(gb[k].z, P1.z);
                float y2 = fminf(gb[k].w, P1.w);
                float iw = fmaxf(x2 - x1, 0.0f);
                float ih = fmaxf(y2 - y1, 0.0f);
                iv[k] = iw * ih;
                uv[k] = (ga[k] + a1) - iv[k];
            }
            Cand c01 = merge_up(Cand{iv[0], uv[0], g0 + 0}, Cand{iv[1], uv[1], g0 + 1});
            Cand c23 = merge_up(Cand{iv[2], uv[2], g0 + 2}, Cand{iv[3], uv[3], g0 + 3});
            Cand c45 = merge_up(Cand{iv[4], uv[4], g0 + 4}, Cand{iv[5], uv[5], g0 + 5});
            Cand c67 = merge_up(Cand{iv[6], uv[6], g0 + 6}, Cand{iv[7], uv[7], g0 + 7});
            Cand c03 = merge_up(c01, c23);
            Cand c47 = merge_up(c45, c67);
            best1 = merge_up(best1, merge_up(c03, c47));
        }
    }

    s_part[qt][slot0] = make_float4(best0.i, best0.u, __int_as_float(best0.g), 0.0f);
    s_part[qt][slot1] = make_float4(best1.i, best1.u, __int_as_float(best1.g), 0.0f);
    __syncthreads();

    // Combine: thread tid owns proposal base+tid; halves merged ascending.
    const int n = base + tid;
    if (n < N) {
        float4 v0 = s_part[0][tid];
        float4 v1 = s_part[1][tid];
        Cand lo = {v0.x, v0.y, __float_as_int(v0.z)};
        Cand hi = {v1.x, v1.y, __float_as_int(v1.z)};
        Cand best = merge_up(lo, hi);

        float iou = best.i / best.u;       // IEEE div == reference max

        float lab;
        if (iou < LOW_BG_IOU)          lab = -1.0f;           // ignored
        else if (iou < IOU_THRESHOLD)  lab = 0.0f;            // background
        else                           lab = s_lab[best.g];

        out[n] = lab;
        ((float4*)(out + N))[n] = s_gt[best.g];  // 800000 B offset, aligned
    }
}

extern "C" void kernel_launch(void* const* d_in, const int* in_sizes, int n_in,
                              void* d_out, int out_size, void* d_ws, size_t ws_size,
                              hipStream_t stream) {
    const float* proposals = (const float*)d_in[0];
    const float* gt_boxes  = (const float*)d_in[1];
    const int*   gt_labels = (const int*)d_in[2];
    float* out = (float*)d_out;

    int N = in_sizes[0] / 4;               // 200000
    int blocks = (N + PROPS - 1) / PROPS;  // 782

    roi_match_kernel<<<blocks, BLOCK, 0, stream>>>(proposals, gt_boxes,
                                                   gt_labels, out, N);
}

// Round 11
// 74.633 us; speedup vs baseline: 1.0539x; 1.0539x over previous
//
#include <hip/hip_runtime.h>

// ROI head matcher. R11: deconfound R10 — tournament tree at R4's exact
// grid/layout. Block = 256 thr = 4 waves; 64 proposals/block (lane <->
// proposal, all waves); wave w scans GT quarter [32w,32w+32); 3125 blocks
// = 12.5k waves (~12/CU, ~6% tail — R10's 782-block grid had ~33% tail,
// which confounded the tree test). Only change vs R4: the reduction shape.
//   Per group of 4 GTs: 4 independent IoUs, depth-2 Dekker tree, 1 carried
//   merge -> carried chain 8 merges instead of 32 compares (4x serial cut,
//   equal issue count). garea from LDS (s_area) keeps per-GT VALU ~21 ops.
// All pairings/merges ascending-index with strict '>' -> jnp.argmax
// first-index tie semantics exact.
//
// Pair compare (exact, absmax 0 across R2-R10):
//   i1/u1 > i2/u2  <=>  (p1+e1) > (p2+e2),  e = fmaf(a,b,-p)
// One IEEE divide in the epilogue reproduces best_match_iou bit-exactly.

#define IOU_THRESHOLD 0.5f
#define LOW_BG_IOU 0.1f
#define BLOCK 256
#define NPROP 64    // proposals per block

struct Cand { float i, u; int g; };

__device__ __forceinline__ Cand merge_up(Cand a, Cand b) {
    // b has strictly higher indices; replaces a only if strictly greater.
    float p1 = b.i * a.u;
    float e1 = fmaf(b.i, a.u, -p1);
    float p2 = a.i * b.u;
    float e2 = fmaf(a.i, b.u, -p2);
    bool gt = (p1 - p2) > (e2 - e1);
    Cand r;
    r.i = gt ? b.i : a.i;
    r.u = gt ? b.u : a.u;
    r.g = gt ? b.g : a.g;
    return r;
}

__global__ __launch_bounds__(BLOCK) void roi_match_kernel(
    const float* __restrict__ proposals,   // [N,4]
    const float* __restrict__ gt_boxes,    // [128,4]
    const int*   __restrict__ gt_labels,   // [128]
    float* __restrict__ out,               // [N] labels then [N,4] boxes
    int N)
{
#pragma clang fp contract(off)
    __shared__ float4 s_gt[128];
    __shared__ float  s_area[128];
    __shared__ float  s_lab[128];
    __shared__ float4 s_part[4][NPROP];    // [gt-quarter][proposal lane]

    const int tid  = threadIdx.x;
    const int wave = tid >> 6;
    const int lane = tid & 63;
    const int base = blockIdx.x * NPROP;

    if (tid < 128) {
        float4 b = ((const float4*)gt_boxes)[tid];
        s_gt[tid]   = b;
        s_area[tid] = (b.z - b.x) * (b.w - b.y);   // reference rounding
        s_lab[tid]  = (float)gt_labels[tid];
    }
    __syncthreads();

    const int n  = base + lane;
    const int nc = n < N ? n : N - 1;      // clamp loads; writes guarded
    const float4 P = ((const float4*)proposals)[nc];
    const float area_p = (P.z - P.x) * (P.w - P.y);

    const int gbase = wave * 32;
    Cand best = {0.0f, 1.0f, gbase};       // iou-0 sentinel at first index

#pragma unroll 2
    for (int grp = 0; grp < 8; ++grp) {    // 8 groups of 4 GTs
        const int g0 = gbase + grp * 4;

        float4 gb0 = s_gt[g0 + 0];
        float4 gb1 = s_gt[g0 + 1];
        float4 gb2 = s_gt[g0 + 2];
        float4 gb3 = s_gt[g0 + 3];
        float ar0 = s_area[g0 + 0];
        float ar1 = s_area[g0 + 1];
        float ar2 = s_area[g0 + 2];
        float ar3 = s_area[g0 + 3];

        float iv[4], uv[4];
        {
            float x1 = fmaxf(gb0.x, P.x), y1 = fmaxf(gb0.y, P.y);
            float x2 = fminf(gb0.z, P.z), y2 = fminf(gb0.w, P.w);
            float iw = fmaxf(x2 - x1, 0.0f), ih = fmaxf(y2 - y1, 0.0f);
            iv[0] = iw * ih; uv[0] = (ar0 + area_p) - iv[0];
        }
        {
            float x1 = fmaxf(gb1.x, P.x), y1 = fmaxf(gb1.y, P.y);
            float x2 = fminf(gb1.z, P.z), y2 = fminf(gb1.w, P.w);
            float iw = fmaxf(x2 - x1, 0.0f), ih = fmaxf(y2 - y1, 0.0f);
            iv[1] = iw * ih; uv[1] = (ar1 + area_p) - iv[1];
        }
        {
            float x1 = fmaxf(gb2.x, P.x), y1 = fmaxf(gb2.y, P.y);
            float x2 = fminf(gb2.z, P.z), y2 = fminf(gb2.w, P.w);
            float iw = fmaxf(x2 - x1, 0.0f), ih = fmaxf(y2 - y1, 0.0f);
            iv[2] = iw * ih; uv[2] = (ar2 + area_p) - iv[2];
        }
        {
            float x1 = fmaxf(gb3.x, P.x), y1 = fmaxf(gb3.y, P.y);
            float x2 = fminf(gb3.z, P.z), y2 = fminf(gb3.w, P.w);
            float iw = fmaxf(x2 - x1, 0.0f), ih = fmaxf(y2 - y1, 0.0f);
            iv[3] = iw * ih; uv[3] = (ar3 + area_p) - iv[3];
        }

        // depth-2 tree, ascending order, then one carried merge
        Cand c01 = merge_up(Cand{iv[0], uv[0], g0 + 0}, Cand{iv[1], uv[1], g0 + 1});
        Cand c23 = merge_up(Cand{iv[2], uv[2], g0 + 2}, Cand{iv[3], uv[3], g0 + 3});
        Cand c   = merge_up(c01, c23);
        best = merge_up(best, c);
    }

    s_part[wave][lane] = make_float4(best.i, best.u, __int_as_float(best.g), 0.0f);
    __syncthreads();

    // Combine: wave 0 lanes own proposals; quarters merged in ascending order.
    if (wave == 0 && n < N) {
        float4 v0 = s_part[0][lane];
        Cand b = {v0.x, v0.y, __float_as_int(v0.z)};
#pragma unroll
        for (int q = 1; q < 4; ++q) {
            float4 v = s_part[q][lane];
            b = merge_up(b, Cand{v.x, v.y, __float_as_int(v.z)});
        }
        float iou = b.i / b.u;             // IEEE div == reference max

        float lab;
        if (iou < LOW_BG_IOU)          lab = -1.0f;         // ignored
        else if (iou < IOU_THRESHOLD)  lab = 0.0f;          // background
        else                           lab = s_lab[b.g];

        out[n] = lab;
        ((float4*)(out + N))[n] = s_gt[b.g];   // 800000 B offset, 16B-aligned
    }
}

extern "C" void kernel_launch(void* const* d_in, const int* in_sizes, int n_in,
                              void* d_out, int out_size, void* d_ws, size_t ws_size,
                              hipStream_t stream) {
    const float* proposals = (const float*)d_in[0];
    const float* gt_boxes  = (const float*)d_in[1];
    const int*   gt_labels = (const int*)d_in[2];
    float* out = (float*)d_out;

    int N = in_sizes[0] / 4;               // 200000
    int blocks = (N + NPROP - 1) / NPROP;  // 3125 (exact)

    roi_match_kernel<<<blocks, BLOCK, 0, stream>>>(proposals, gt_boxes,
                                                   gt_labels, out, N);
}